// Round 16
// baseline (218.560 us; speedup 1.0000x reference)
//
#include <hip/hip_runtime.h>
#include <hip/hip_bf16.h>
#include <cmath>

#define BETA 0.3f
#define LAMBDA_PHY 0.15f

#define BM 128
#define BN 128
#define BKE 128          // K elems per tile (fp8 -> 128 B rows, 8x16B slots)
#define NT 512

typedef float f32x4 __attribute__((ext_vector_type(4)));
typedef long  i64x2 __attribute__((ext_vector_type(2)));

#define AS1 __attribute__((address_space(1)))
#define AS3 __attribute__((address_space(3)))

#define FENCE() asm volatile("" ::: "memory")
#define BARRIER() do { FENCE(); __builtin_amdgcn_s_barrier(); FENCE(); } while (0)
#define WAITV4() asm volatile("s_waitcnt vmcnt(4)" ::: "memory")
#define WAITV0() asm volatile("s_waitcnt vmcnt(0)" ::: "memory")

__device__ __forceinline__ float softplus_f(float x) {
    return fmaxf(x, 0.0f) + __logf(1.0f + __expf(-fabsf(x)));
}

__device__ __forceinline__ float smooth_l1_f(float d) {
    float ad = fabsf(d);
    return (ad < BETA) ? (0.5f / BETA) * d * d : (ad - 0.5f * BETA);
}

__device__ __forceinline__ unsigned short f2bf_rn(float f) {
    unsigned int u = __builtin_bit_cast(unsigned int, f);
    return (unsigned short)((u + 0x7FFFu + ((u >> 16) & 1u)) >> 16);
}

__device__ __forceinline__ float bf2f(unsigned short u) {
    return __builtin_bit_cast(float, (unsigned int)u << 16);
}

// e4m3fn encode (RNE, saturating) — exact bit manipulation.
__device__ __forceinline__ unsigned f_e4m3(float f) {
    unsigned u = __builtin_bit_cast(unsigned, f);
    unsigned s = (u >> 24) & 0x80u;
    unsigned ab = u & 0x7fffffffu;
    float a = __builtin_bit_cast(float, ab);
    if (a >= 448.f) return s | 0x7Eu;
    if (a < 0.015625f) {                       // below min normal 2^-6 -> subnormal
        int q = (int)rintf(a * 512.f);         // lsb 2^-9; q==8 -> 0x08 == 2^-6
        return s | (unsigned)q;
    }
    unsigned r = ab + 0x7FFFFu + ((ab >> 20) & 1u);   // RNE at 3 mantissa bits
    unsigned ee = (r >> 23) - 120u;                    // e-127+7
    unsigned m = (r >> 20) & 7u;
    return s | (ee << 3) | m;
}

// ---------------------------------------------------------------------------
// Kernel 1 (fused): blocks [0,Z): adjacency row -> e4m3 mask + invdeg + hasnb.
//                   blocks [Z,Z+ncb): ctemps fp32 -> e4m3 (GEMM) + bf16
//                   (epilogue c), 16 elems/thread.
__global__ void k_prepconv(const int* __restrict__ adj, unsigned char* __restrict__ maskf8,
                           float* __restrict__ invdeg, float* __restrict__ hasnb, int Z,
                           const float* __restrict__ src, uint4* __restrict__ dst8,
                           uint4* __restrict__ dstb, long n16, int ncb) {
    int t = threadIdx.x;
    if ((int)blockIdx.x < Z) {
        int z = blockIdx.x;
        const int* row = adj + (size_t)z * Z;
        unsigned char* mrow = maskf8 + (size_t)z * Z;
        int cnt = 0;
        for (int n = t; n < Z; n += blockDim.x) {
            int a = (row[n] > 0);
            mrow[n] = a ? (unsigned char)0x38 : (unsigned char)0;   // e4m3 1.0 / 0.0
            cnt += a;
        }
        for (int o = 32; o; o >>= 1) cnt += __shfl_down(cnt, o);
        __shared__ int rs[4];
        int lane = t & 63, wave = t >> 6;
        if (lane == 0) rs[wave] = cnt;
        __syncthreads();
        if (t == 0) {
            int deg = rs[0] + rs[1] + rs[2] + rs[3];
            invdeg[z] = (deg > 0) ? 1.0f / (float)deg : 1.0f;
            hasnb[z]  = (deg > 0) ? 1.0f : 0.0f;
        }
    } else {
        long i = (long)(blockIdx.x - Z) * blockDim.x + t;
        long stride = (long)ncb * blockDim.x;
        for (; i < n16; i += stride) {
            const float4* s = (const float4*)(src + i * 16);
            float4 v0 = s[0], v1 = s[1], v2 = s[2], v3 = s[3];
            uint4 o8;
            o8.x = f_e4m3(v0.x) | (f_e4m3(v0.y) << 8) | (f_e4m3(v0.z) << 16) | (f_e4m3(v0.w) << 24);
            o8.y = f_e4m3(v1.x) | (f_e4m3(v1.y) << 8) | (f_e4m3(v1.z) << 16) | (f_e4m3(v1.w) << 24);
            o8.z = f_e4m3(v2.x) | (f_e4m3(v2.y) << 8) | (f_e4m3(v2.z) << 16) | (f_e4m3(v2.w) << 24);
            o8.w = f_e4m3(v3.x) | (f_e4m3(v3.y) << 8) | (f_e4m3(v3.z) << 16) | (f_e4m3(v3.w) << 24);
            dst8[i] = o8;
            uint4 b0, b1;
            b0.x = (unsigned)f2bf_rn(v0.x) | ((unsigned)f2bf_rn(v0.y) << 16);
            b0.y = (unsigned)f2bf_rn(v0.z) | ((unsigned)f2bf_rn(v0.w) << 16);
            b0.z = (unsigned)f2bf_rn(v1.x) | ((unsigned)f2bf_rn(v1.y) << 16);
            b0.w = (unsigned)f2bf_rn(v1.z) | ((unsigned)f2bf_rn(v1.w) << 16);
            b1.x = (unsigned)f2bf_rn(v2.x) | ((unsigned)f2bf_rn(v2.y) << 16);
            b1.y = (unsigned)f2bf_rn(v2.z) | ((unsigned)f2bf_rn(v2.w) << 16);
            b1.z = (unsigned)f2bf_rn(v3.x) | ((unsigned)f2bf_rn(v3.y) << 16);
            b1.w = (unsigned)f2bf_rn(v3.z) | ((unsigned)f2bf_rn(v3.w) << 16);
            dstb[2 * i] = b0;
            dstb[2 * i + 1] = b1;
        }
    }
}

// ---------------------------------------------------------------------------
// Kernel 2: 128x128 fp8(e4m3) GEMM, BK=128 elems, 8 waves (2x4), per-wave
// 64x32 out, 2 blocks/CU. K-loop = R15 champion (b128 K-chunk-remapped reads,
// conflict-free XOR swizzle, counted vmcnt(4), compile-time buffer unroll,
// T1 XCD swizzle, setprio). R16 change: BATCHED epilogue — all 48 loads of an
// n-group issued into registers before compute (R15: VGPR 52 -> serial load
// bursts, MFMA idle); c read as bf16 (1-op decode, -67 MB fetch vs fp32).
__global__ __launch_bounds__(NT, 4) void k_gemm(
    const unsigned char* __restrict__ Af8,    // [M][K] e4m3 ctemps
    const unsigned char* __restrict__ Bf8,    // [N][K] e4m3 mask
    const float* __restrict__ preds,
    const float* __restrict__ targets,
    const unsigned short* __restrict__ cbf,   // [M][N-dim? no: [M][K]] bf16 ctemps
    const float* __restrict__ invdeg,
    const float* __restrict__ hasnb,
    float* __restrict__ partials,
    int M, int N, int K)
{
    __shared__ __align__(16) unsigned char AsF[2 * BM * BKE];   // 32 KB
    __shared__ __align__(16) unsigned char BsF[2 * BN * BKE];   // 32 KB

    const int nwg = gridDim.x;
    const int ob = blockIdx.x;
    const int bid = (nwg % 8 == 0) ? ((ob % 8) * (nwg / 8) + ob / 8) : ob;  // T1
    const int ntiles = N / BN;
    const int mt = bid / ntiles;
    const int nt = bid % ntiles;
    const int row0 = mt * BM;
    const int col0 = nt * BN;
    const int t = threadIdx.x;
    const int lane = t & 63;
    const int wave = t >> 6;
    const int wm = wave >> 2;             // 2x4 wave grid; per-wave 64x32 out
    const int wn = wave & 3;
    const int fr = lane & 15;
    const int fq = lane >> 4;
    const int fr7 = fr & 7;

    // staging: thread t -> row tr (0..63, +64 2nd chunk), 16B slot tc (0..7);
    // source slot pre-swizzled (T2): cs = tc ^ (tr&7).
    const int tr = t >> 3;
    const int tc = t & 7;
    const int cs = tc ^ (tr & 7);

    // loop-invariant LDS read byte-offsets: one b128 per (row, p), logical
    // slot fq+4p, physical slot (fq+4p)^(row&7); row&7 == fr&7.
    int ofsA[2], ofsB[2];
#pragma unroll
    for (int p = 0; p < 2; ++p) {
        const int sp = (((fq + 4 * p) ^ fr7) << 4);
        ofsA[p] = (wm * 64 + fr) * BKE + sp;   // + mi*2048 (16 rows)
        ofsB[p] = (wn * 32 + fr) * BKE + sp;   // + ni*2048
    }

    f32x4 acc[4][2];
#pragma unroll
    for (int m = 0; m < 4; ++m)
#pragma unroll
        for (int n = 0; n < 2; ++n)
            acc[m][n] = (f32x4){0.f, 0.f, 0.f, 0.f};

    // per-thread byte source pointers (advance by BKE bytes per staged tile)
    const unsigned char* aSrc = Af8 + (size_t)(row0 + tr) * K + cs * 16;
    const unsigned char* bSrc = Bf8 + (size_t)(col0 + tr) * K + cs * 16;
    unsigned char* aDstC = &AsF[t * 16];
    unsigned char* bDstC = &BsF[t * 16];

#define STAGE(BUF) do {                                                                      \
    __builtin_amdgcn_global_load_lds((const AS1 void*)(aSrc),                                \
                                     (AS3 void*)(aDstC + (BUF) * 16384), 16, 0, 0);          \
    __builtin_amdgcn_global_load_lds((const AS1 void*)(aSrc + (size_t)64 * K),               \
                                     (AS3 void*)(aDstC + (BUF) * 16384 + 8192), 16, 0, 0);   \
    __builtin_amdgcn_global_load_lds((const AS1 void*)(bSrc),                                \
                                     (AS3 void*)(bDstC + (BUF) * 16384), 16, 0, 0);          \
    __builtin_amdgcn_global_load_lds((const AS1 void*)(bSrc + (size_t)64 * K),               \
                                     (AS3 void*)(bDstC + (BUF) * 16384 + 8192), 16, 0, 0);   \
    aSrc += BKE; bSrc += BKE;                                                                \
} while (0)

// One K=128 tile: 2 p-steps x {6 ds_read_b128 + 16 MFMA (h=0 then h=1)}.
#define MFMA_TILE(BUF) do {                                                                  \
    _Pragma("unroll")                                                                        \
    for (int p_ = 0; p_ < 2; ++p_) {                                                         \
        i64x2 af_[4], bv_[2];                                                                \
        _Pragma("unroll")                                                                    \
        for (int mi_ = 0; mi_ < 4; ++mi_)                                                    \
            af_[mi_] = *(const i64x2*)(AsF + (BUF) * 16384 + ofsA[p_] + mi_ * 2048);         \
        _Pragma("unroll")                                                                    \
        for (int ni_ = 0; ni_ < 2; ++ni_)                                                    \
            bv_[ni_] = *(const i64x2*)(BsF + (BUF) * 16384 + ofsB[p_] + ni_ * 2048);         \
        __builtin_amdgcn_s_setprio(1);                                                       \
        _Pragma("unroll")                                                                    \
        for (int mi_ = 0; mi_ < 4; ++mi_)                                                    \
        _Pragma("unroll")                                                                    \
        for (int ni_ = 0; ni_ < 2; ++ni_)                                                    \
            acc[mi_][ni_] = __builtin_amdgcn_mfma_f32_16x16x32_fp8_fp8(                      \
                af_[mi_][0], bv_[ni_][0], acc[mi_][ni_], 0, 0, 0);                           \
        _Pragma("unroll")                                                                    \
        for (int mi_ = 0; mi_ < 4; ++mi_)                                                    \
        _Pragma("unroll")                                                                    \
        for (int ni_ = 0; ni_ < 2; ++ni_)                                                    \
            acc[mi_][ni_] = __builtin_amdgcn_mfma_f32_16x16x32_fp8_fp8(                      \
                af_[mi_][1], bv_[ni_][1], acc[mi_][ni_], 0, 0, 0);                           \
        __builtin_amdgcn_s_setprio(0);                                                       \
    }                                                                                        \
} while (0)

    const int nk = K / BKE;         // 16 at Z=2048; even (guarded)
    const int nk2 = nk >> 1;
    STAGE(0);                        // tile 0 -> buf 0

    for (int i = 0; i < nk2; ++i) {
        STAGE(1);
        WAITV4();                    // retires tile 2i's 4 loads (oldest in FIFO)
        BARRIER();
        MFMA_TILE(0);
        BARRIER();
        if (i + 1 < nk2) {
            STAGE(0);
            WAITV4();
        } else {
            WAITV0();
        }
        BARRIER();
        MFMA_TILE(1);
        BARRIER();
    }

#undef STAGE
#undef MFMA_TILE

    // Batched fused epilogue. C/D layout: col=lane&15, row=(lane>>4)*4+reg.
    // block row = wm*64 + m*16 + fq*4 + j ; block col = wn*32 + n*16 + fr
    float vsum = 0.f, ssum = 0.f;
#pragma unroll
    for (int n = 0; n < 2; ++n) {
        const int z = col0 + wn * 32 + n * 16 + fr;
        const float idg = invdeg[z];
        const float hnb = hasnb[z];
        // phase 1: issue all 48 independent loads of this n-group
        float pv[16], tv[16], cf[16];
#pragma unroll
        for (int m = 0; m < 4; ++m) {
            const int rb = row0 + wm * 64 + m * 16 + fq * 4;
#pragma unroll
            for (int j = 0; j < 4; ++j) {
                const size_t idx = (size_t)(rb + j) * N + z;
                pv[m * 4 + j] = preds[idx];
                tv[m * 4 + j] = targets[idx];
                cf[m * 4 + j] = bf2f(cbf[idx]);
            }
        }
        // phase 2: compute
#pragma unroll
        for (int m = 0; m < 4; ++m)
#pragma unroll
            for (int j = 0; j < 4; ++j) {
                const int q = m * 4 + j;
                float avg = acc[m][n][j] * idg;
                float c = cf[q];
                float p = pv[q];
                float x = (c - avg) * (p - c);
                vsum += softplus_f(x) * hnb;
                ssum += smooth_l1_f(p - tv[q]);
            }
    }
    for (int o = 32; o; o >>= 1) { vsum += __shfl_down(vsum, o); ssum += __shfl_down(ssum, o); }
    __shared__ float rv[8], rsm[8];
    if (lane == 0) { rv[wave] = vsum; rsm[wave] = ssum; }
    __syncthreads();
    if (t == 0) {
        float v = 0.f, s = 0.f;
#pragma unroll
        for (int w = 0; w < 8; ++w) { v += rv[w]; s += rsm[w]; }
        partials[2 * (size_t)ob]     = v;
        partials[2 * (size_t)ob + 1] = s;
    }
}

// ---------------------------------------------------------------------------
// Kernel 3: deterministic fixed-order final reduction
__global__ void k_finalize(const float* __restrict__ partials, int nblk,
                           float* __restrict__ out, float invBZ) {
    __shared__ float sv[256], ss[256];
    int t = threadIdx.x;
    float v = 0.f, s = 0.f;
    for (int i = t; i < nblk; i += 256) { v += partials[2 * (size_t)i]; s += partials[2 * (size_t)i + 1]; }
    sv[t] = v; ss[t] = s;
    __syncthreads();
    for (int o = 128; o; o >>= 1) {
        if (t < o) { sv[t] += sv[t + o]; ss[t] += ss[t + o]; }
        __syncthreads();
    }
    if (t == 0) {
        float phys = sv[0] * invBZ;
        float pred = ss[0] * invBZ;
        out[0] = pred + LAMBDA_PHY * phys;
        out[1] = phys;
    }
}

// ---------------------------------------------------------------------------
// Fallback path (only if ws too small / odd shapes): fp32, atomics into ws[0..1]
__global__ void k_zero2(float* p) { if (threadIdx.x < 2) p[threadIdx.x] = 0.f; }

__global__ void k_fallback(const float* __restrict__ preds, const float* __restrict__ targets,
                           const float* __restrict__ ctemps, const int* __restrict__ adj,
                           float* __restrict__ acc2, int B, int Z) {
    extern __shared__ float crow[];
    int nzb = (Z + 255) / 256;
    int b = blockIdx.x / nzb;
    int zb = blockIdx.x % nzb;
    int t = threadIdx.x;
    const float* cr = ctemps + (size_t)b * Z;
    for (int n = t; n < Z; n += 256) crow[n] = cr[n];
    __syncthreads();
    int z = zb * 256 + t;
    float vsum = 0.f, ssum = 0.f;
    if (z < Z) {
        const int* arow = adj + (size_t)z * Z;
        float sum = 0.f; int deg = 0;
        for (int n = 0; n < Z; ++n) {
            if (arow[n] > 0) { sum += crow[n]; ++deg; }
        }
        float avg = (deg > 0) ? sum / (float)deg : 0.f;
        float c = crow[z];
        size_t idx = (size_t)b * Z + z;
        float p = preds[idx];
        float x = (c - avg) * (p - c);
        vsum = (deg > 0) ? softplus_f(x) : 0.f;
        ssum = smooth_l1_f(p - targets[idx]);
    }
    for (int o = 32; o; o >>= 1) { vsum += __shfl_down(vsum, o); ssum += __shfl_down(ssum, o); }
    __shared__ float rv[4], rs2[4];
    int lane = t & 63, wave = t >> 6;
    if (lane == 0) { rv[wave] = vsum; rs2[wave] = ssum; }
    __syncthreads();
    if (t == 0) {
        atomicAdd(&acc2[0], rv[0] + rv[1] + rv[2] + rv[3]);
        atomicAdd(&acc2[1], rs2[0] + rs2[1] + rs2[2] + rs2[3]);
    }
}

// ---------------------------------------------------------------------------
extern "C" void kernel_launch(void* const* d_in, const int* in_sizes, int n_in,
                              void* d_out, int out_size, void* d_ws, size_t ws_size,
                              hipStream_t stream) {
    const float* preds   = (const float*)d_in[0];
    const float* targets = (const float*)d_in[1];
    const float* ctemps  = (const float*)d_in[2];
    const int*   adj     = (const int*)d_in[3];
    float* out = (float*)d_out;

    long zz = in_sizes[3];
    int Z = (int)llround(sqrt((double)zz));
    int B = in_sizes[1] / Z;

    size_t off = 0;
    size_t maskOff = off; off += (size_t)Z * Z;          // fp8 mask
    size_t cf8Off  = off; off += (size_t)B * Z;          // fp8 ctemps
    size_t cbfOff  = off; off += (size_t)B * Z * 2;      // bf16 ctemps (epilogue)
    size_t idgOff  = off; off += (size_t)Z * 4;
    size_t hnbOff  = off; off += (size_t)Z * 4;
    int nblk = (Z > 0 && B > 0 && (B % BM) == 0 && (Z % BN) == 0) ? (B / BM) * (Z / BN) : 0;
    size_t partOff = off; off += (size_t)(nblk > 0 ? nblk : 1) * 2 * 4;

    bool main_ok = (B % BM == 0) && (Z % BN == 0) && (Z % BKE == 0) &&
                   (((Z / BKE) % 2) == 0) && ((B * Z) % 16 == 0) && (ws_size >= off);

    float invBZ = (float)(1.0 / ((double)B * (double)Z));

    if (main_ok) {
        char* ws = (char*)d_ws;
        unsigned char* maskf8 = (unsigned char*)(ws + maskOff);
        unsigned char* cf8    = (unsigned char*)(ws + cf8Off);
        unsigned short* cbf   = (unsigned short*)(ws + cbfOff);
        float* idg      = (float*)(ws + idgOff);
        float* hnb      = (float*)(ws + hnbOff);
        float* partials = (float*)(ws + partOff);

        long n16 = (long)B * Z / 16;
        int ncb = 2048;
        k_prepconv<<<Z + ncb, 256, 0, stream>>>(adj, maskf8, idg, hnb, Z,
                                                ctemps, (uint4*)cf8, (uint4*)cbf, n16, ncb);
        k_gemm<<<nblk, NT, 0, stream>>>(cf8, maskf8, preds, targets, cbf, idg, hnb,
                                        partials, B, Z, Z);
        k_finalize<<<1, 256, 0, stream>>>(partials, nblk, out, invBZ);
    } else {
        float* acc2 = (float*)d_ws;
        k_zero2<<<1, 64, 0, stream>>>(acc2);
        int nzb = (Z + 255) / 256;
        k_fallback<<<B * nzb, 256, (size_t)Z * 4, stream>>>(preds, targets, ctemps, adj, acc2, B, Z);
        k_finalize<<<1, 256, 0, stream>>>(acc2, 1, out, invBZ);
    }
}

// Round 17
// 203.655 us; speedup vs baseline: 1.0732x; 1.0732x over previous
//
#include <hip/hip_runtime.h>
#include <hip/hip_bf16.h>
#include <cmath>

#define BETA 0.3f
#define LAMBDA_PHY 0.15f

#define BM 128
#define BN 128
#define BKE 128          // K elems per tile (fp8 -> 128 B rows, 8x16B slots)
#define NT 512

typedef float f32x4 __attribute__((ext_vector_type(4)));
typedef long  i64x2 __attribute__((ext_vector_type(2)));

#define AS1 __attribute__((address_space(1)))
#define AS3 __attribute__((address_space(3)))

#define FENCE() asm volatile("" ::: "memory")
#define BARRIER() do { FENCE(); __builtin_amdgcn_s_barrier(); FENCE(); } while (0)
#define WAITV4() asm volatile("s_waitcnt vmcnt(4)" ::: "memory")
#define WAITV0() asm volatile("s_waitcnt vmcnt(0)" ::: "memory")

__device__ __forceinline__ float softplus_f(float x) {
    return fmaxf(x, 0.0f) + __logf(1.0f + __expf(-fabsf(x)));
}

__device__ __forceinline__ float smooth_l1_f(float d) {
    float ad = fabsf(d);
    return (ad < BETA) ? (0.5f / BETA) * d * d : (ad - 0.5f * BETA);
}

// e4m3fn encode (RNE, saturating) — exact bit manipulation.
__device__ __forceinline__ unsigned f_e4m3(float f) {
    unsigned u = __builtin_bit_cast(unsigned, f);
    unsigned s = (u >> 24) & 0x80u;
    unsigned ab = u & 0x7fffffffu;
    float a = __builtin_bit_cast(float, ab);
    if (a >= 448.f) return s | 0x7Eu;
    if (a < 0.015625f) {                       // below min normal 2^-6 -> subnormal
        int q = (int)rintf(a * 512.f);         // lsb 2^-9; q==8 -> 0x08 == 2^-6
        return s | (unsigned)q;
    }
    unsigned r = ab + 0x7FFFFu + ((ab >> 20) & 1u);   // RNE at 3 mantissa bits
    unsigned ee = (r >> 23) - 120u;                    // e-127+7
    unsigned m = (r >> 20) & 7u;
    return s | (ee << 3) | m;
}

// ---------------------------------------------------------------------------
// Kernel 1 (fused): blocks [0,Z): adjacency row -> e4m3 mask + invdeg + hasnb.
//                   blocks [Z,Z+ncb): ctemps fp32 -> e4m3 (16 elems/thread).
__global__ void k_prepconv(const int* __restrict__ adj, unsigned char* __restrict__ maskf8,
                           float* __restrict__ invdeg, float* __restrict__ hasnb, int Z,
                           const float* __restrict__ src, uint4* __restrict__ dst,
                           long n16, int ncb) {
    int t = threadIdx.x;
    if ((int)blockIdx.x < Z) {
        int z = blockIdx.x;
        const int* row = adj + (size_t)z * Z;
        unsigned char* mrow = maskf8 + (size_t)z * Z;
        int cnt = 0;
        for (int n = t; n < Z; n += blockDim.x) {
            int a = (row[n] > 0);
            mrow[n] = a ? (unsigned char)0x38 : (unsigned char)0;   // e4m3 1.0 / 0.0
            cnt += a;
        }
        for (int o = 32; o; o >>= 1) cnt += __shfl_down(cnt, o);
        __shared__ int rs[4];
        int lane = t & 63, wave = t >> 6;
        if (lane == 0) rs[wave] = cnt;
        __syncthreads();
        if (t == 0) {
            int deg = rs[0] + rs[1] + rs[2] + rs[3];
            invdeg[z] = (deg > 0) ? 1.0f / (float)deg : 1.0f;
            hasnb[z]  = (deg > 0) ? 1.0f : 0.0f;
        }
    } else {
        long i = (long)(blockIdx.x - Z) * blockDim.x + t;
        long stride = (long)ncb * blockDim.x;
        for (; i < n16; i += stride) {
            const float4* s = (const float4*)(src + i * 16);
            uint4 o;
            unsigned w[4];
#pragma unroll
            for (int q = 0; q < 4; ++q) {
                float4 v = s[q];
                w[q] = f_e4m3(v.x) | (f_e4m3(v.y) << 8) | (f_e4m3(v.z) << 16) | (f_e4m3(v.w) << 24);
            }
            o.x = w[0]; o.y = w[1]; o.z = w[2]; o.w = w[3];
            dst[i] = o;
        }
    }
}

// ---------------------------------------------------------------------------
// Kernel 2: 128x128 fp8(e4m3) GEMM, BK=128 elems, 8 waves (2x4), per-wave
// 64x32 out, 2 blocks/CU. K-loop = R15 champion (b128 K-chunk-remapped reads,
// conflict-free XOR swizzle, counted vmcnt(4), compile-time buffer unroll,
// T1 XCD swizzle, setprio). R17: epilogue in 4 batches of 8 outputs (24 loads
// per batch — R16's 48-value batch spilled 41 MB; 24 stays under the spill
// threshold). Batches independent -> scheduler overlaps loads with compute.
__global__ __launch_bounds__(NT, 4) void k_gemm(
    const unsigned char* __restrict__ Af8,    // [M][K] e4m3 ctemps
    const unsigned char* __restrict__ Bf8,    // [N][K] e4m3 mask
    const float* __restrict__ preds,
    const float* __restrict__ targets,
    const float* __restrict__ ctemps,         // fp32 (epilogue c)
    const float* __restrict__ invdeg,
    const float* __restrict__ hasnb,
    float* __restrict__ partials,
    int M, int N, int K)
{
    __shared__ __align__(16) unsigned char AsF[2 * BM * BKE];   // 32 KB
    __shared__ __align__(16) unsigned char BsF[2 * BN * BKE];   // 32 KB

    const int nwg = gridDim.x;
    const int ob = blockIdx.x;
    const int bid = (nwg % 8 == 0) ? ((ob % 8) * (nwg / 8) + ob / 8) : ob;  // T1
    const int ntiles = N / BN;
    const int mt = bid / ntiles;
    const int nt = bid % ntiles;
    const int row0 = mt * BM;
    const int col0 = nt * BN;
    const int t = threadIdx.x;
    const int lane = t & 63;
    const int wave = t >> 6;
    const int wm = wave >> 2;             // 2x4 wave grid; per-wave 64x32 out
    const int wn = wave & 3;
    const int fr = lane & 15;
    const int fq = lane >> 4;
    const int fr7 = fr & 7;

    // staging: thread t -> row tr (0..63, +64 2nd chunk), 16B slot tc (0..7);
    // source slot pre-swizzled (T2): cs = tc ^ (tr&7).
    const int tr = t >> 3;
    const int tc = t & 7;
    const int cs = tc ^ (tr & 7);

    // loop-invariant LDS read byte-offsets: one b128 per (row, p), logical
    // slot fq+4p, physical slot (fq+4p)^(row&7); row&7 == fr&7.
    int ofsA[2], ofsB[2];
#pragma unroll
    for (int p = 0; p < 2; ++p) {
        const int sp = (((fq + 4 * p) ^ fr7) << 4);
        ofsA[p] = (wm * 64 + fr) * BKE + sp;   // + mi*2048 (16 rows)
        ofsB[p] = (wn * 32 + fr) * BKE + sp;   // + ni*2048
    }

    f32x4 acc[4][2];
#pragma unroll
    for (int m = 0; m < 4; ++m)
#pragma unroll
        for (int n = 0; n < 2; ++n)
            acc[m][n] = (f32x4){0.f, 0.f, 0.f, 0.f};

    // per-thread byte source pointers (advance by BKE bytes per staged tile)
    const unsigned char* aSrc = Af8 + (size_t)(row0 + tr) * K + cs * 16;
    const unsigned char* bSrc = Bf8 + (size_t)(col0 + tr) * K + cs * 16;
    unsigned char* aDstC = &AsF[t * 16];
    unsigned char* bDstC = &BsF[t * 16];

#define STAGE(BUF) do {                                                                      \
    __builtin_amdgcn_global_load_lds((const AS1 void*)(aSrc),                                \
                                     (AS3 void*)(aDstC + (BUF) * 16384), 16, 0, 0);          \
    __builtin_amdgcn_global_load_lds((const AS1 void*)(aSrc + (size_t)64 * K),               \
                                     (AS3 void*)(aDstC + (BUF) * 16384 + 8192), 16, 0, 0);   \
    __builtin_amdgcn_global_load_lds((const AS1 void*)(bSrc),                                \
                                     (AS3 void*)(bDstC + (BUF) * 16384), 16, 0, 0);          \
    __builtin_amdgcn_global_load_lds((const AS1 void*)(bSrc + (size_t)64 * K),               \
                                     (AS3 void*)(bDstC + (BUF) * 16384 + 8192), 16, 0, 0);   \
    aSrc += BKE; bSrc += BKE;                                                                \
} while (0)

// One K=128 tile: 2 p-steps x {6 ds_read_b128 + 16 MFMA (h=0 then h=1)}.
#define MFMA_TILE(BUF) do {                                                                  \
    _Pragma("unroll")                                                                        \
    for (int p_ = 0; p_ < 2; ++p_) {                                                         \
        i64x2 af_[4], bv_[2];                                                                \
        _Pragma("unroll")                                                                    \
        for (int mi_ = 0; mi_ < 4; ++mi_)                                                    \
            af_[mi_] = *(const i64x2*)(AsF + (BUF) * 16384 + ofsA[p_] + mi_ * 2048);         \
        _Pragma("unroll")                                                                    \
        for (int ni_ = 0; ni_ < 2; ++ni_)                                                    \
            bv_[ni_] = *(const i64x2*)(BsF + (BUF) * 16384 + ofsB[p_] + ni_ * 2048);         \
        __builtin_amdgcn_s_setprio(1);                                                       \
        _Pragma("unroll")                                                                    \
        for (int mi_ = 0; mi_ < 4; ++mi_)                                                    \
        _Pragma("unroll")                                                                    \
        for (int ni_ = 0; ni_ < 2; ++ni_)                                                    \
            acc[mi_][ni_] = __builtin_amdgcn_mfma_f32_16x16x32_fp8_fp8(                      \
                af_[mi_][0], bv_[ni_][0], acc[mi_][ni_], 0, 0, 0);                           \
        _Pragma("unroll")                                                                    \
        for (int mi_ = 0; mi_ < 4; ++mi_)                                                    \
        _Pragma("unroll")                                                                    \
        for (int ni_ = 0; ni_ < 2; ++ni_)                                                    \
            acc[mi_][ni_] = __builtin_amdgcn_mfma_f32_16x16x32_fp8_fp8(                      \
                af_[mi_][1], bv_[ni_][1], acc[mi_][ni_], 0, 0, 0);                           \
        __builtin_amdgcn_s_setprio(0);                                                       \
    }                                                                                        \
} while (0)

    const int nk = K / BKE;         // 16 at Z=2048; even (guarded)
    const int nk2 = nk >> 1;
    STAGE(0);                        // tile 0 -> buf 0

    for (int i = 0; i < nk2; ++i) {
        STAGE(1);
        WAITV4();                    // retires tile 2i's 4 loads (oldest in FIFO)
        BARRIER();
        MFMA_TILE(0);
        BARRIER();
        if (i + 1 < nk2) {
            STAGE(0);
            WAITV4();
        } else {
            WAITV0();
        }
        BARRIER();
        MFMA_TILE(1);
        BARRIER();
    }

#undef STAGE
#undef MFMA_TILE

    // Batched fused epilogue: 4 batches x 8 outputs (24 loads then compute).
    // C/D layout: col=lane&15, row=(lane>>4)*4+reg.
    // block row = wm*64 + m*16 + fq*4 + j ; block col = wn*32 + n*16 + fr
    const size_t rbase = (size_t)(row0 + wm * 64 + fq * 4) * N;
    const float* pB = preds   + rbase;
    const float* tB = targets + rbase;
    const float* cB = ctemps  + rbase;

    float vsum = 0.f, ssum = 0.f;
#pragma unroll
    for (int n = 0; n < 2; ++n) {
        const int z = col0 + wn * 32 + n * 16 + fr;
        const float idg = invdeg[z];
        const float hnb = hasnb[z];
#pragma unroll
        for (int mb = 0; mb < 2; ++mb) {
            float pv[8], tv[8], cf[8];
#pragma unroll
            for (int m2 = 0; m2 < 2; ++m2)
#pragma unroll
                for (int j = 0; j < 4; ++j) {
                    const size_t o = (size_t)((mb * 2 + m2) * 16 + j) * N + z;
                    pv[m2 * 4 + j] = pB[o];
                    tv[m2 * 4 + j] = tB[o];
                    cf[m2 * 4 + j] = cB[o];
                }
#pragma unroll
            for (int m2 = 0; m2 < 2; ++m2)
#pragma unroll
                for (int j = 0; j < 4; ++j) {
                    const int q = m2 * 4 + j;
                    float avg = acc[mb * 2 + m2][n][j] * idg;
                    float c = cf[q];
                    float p = pv[q];
                    float x = (c - avg) * (p - c);
                    vsum += softplus_f(x) * hnb;
                    ssum += smooth_l1_f(p - tv[q]);
                }
        }
    }
    for (int o = 32; o; o >>= 1) { vsum += __shfl_down(vsum, o); ssum += __shfl_down(ssum, o); }
    __shared__ float rv[8], rsm[8];
    if (lane == 0) { rv[wave] = vsum; rsm[wave] = ssum; }
    __syncthreads();
    if (t == 0) {
        float v = 0.f, s = 0.f;
#pragma unroll
        for (int w = 0; w < 8; ++w) { v += rv[w]; s += rsm[w]; }
        partials[2 * (size_t)ob]     = v;
        partials[2 * (size_t)ob + 1] = s;
    }
}

// ---------------------------------------------------------------------------
// Kernel 3: deterministic fixed-order final reduction
__global__ void k_finalize(const float* __restrict__ partials, int nblk,
                           float* __restrict__ out, float invBZ) {
    __shared__ float sv[256], ss[256];
    int t = threadIdx.x;
    float v = 0.f, s = 0.f;
    for (int i = t; i < nblk; i += 256) { v += partials[2 * (size_t)i]; s += partials[2 * (size_t)i + 1]; }
    sv[t] = v; ss[t] = s;
    __syncthreads();
    for (int o = 128; o; o >>= 1) {
        if (t < o) { sv[t] += sv[t + o]; ss[t] += ss[t + o]; }
        __syncthreads();
    }
    if (t == 0) {
        float phys = sv[0] * invBZ;
        float pred = ss[0] * invBZ;
        out[0] = pred + LAMBDA_PHY * phys;
        out[1] = phys;
    }
}

// ---------------------------------------------------------------------------
// Fallback path (only if ws too small / odd shapes): fp32, atomics into ws[0..1]
__global__ void k_zero2(float* p) { if (threadIdx.x < 2) p[threadIdx.x] = 0.f; }

__global__ void k_fallback(const float* __restrict__ preds, const float* __restrict__ targets,
                           const float* __restrict__ ctemps, const int* __restrict__ adj,
                           float* __restrict__ acc2, int B, int Z) {
    extern __shared__ float crow[];
    int nzb = (Z + 255) / 256;
    int b = blockIdx.x / nzb;
    int zb = blockIdx.x % nzb;
    int t = threadIdx.x;
    const float* cr = ctemps + (size_t)b * Z;
    for (int n = t; n < Z; n += 256) crow[n] = cr[n];
    __syncthreads();
    int z = zb * 256 + t;
    float vsum = 0.f, ssum = 0.f;
    if (z < Z) {
        const int* arow = adj + (size_t)z * Z;
        float sum = 0.f; int deg = 0;
        for (int n = 0; n < Z; ++n) {
            if (arow[n] > 0) { sum += crow[n]; ++deg; }
        }
        float avg = (deg > 0) ? sum / (float)deg : 0.f;
        float c = crow[z];
        size_t idx = (size_t)b * Z + z;
        float p = preds[idx];
        float x = (c - avg) * (p - c);
        vsum = (deg > 0) ? softplus_f(x) : 0.f;
        ssum = smooth_l1_f(p - targets[idx]);
    }
    for (int o = 32; o; o >>= 1) { vsum += __shfl_down(vsum, o); ssum += __shfl_down(ssum, o); }
    __shared__ float rv[4], rs2[4];
    int lane = t & 63, wave = t >> 6;
    if (lane == 0) { rv[wave] = vsum; rs2[wave] = ssum; }
    __syncthreads();
    if (t == 0) {
        atomicAdd(&acc2[0], rv[0] + rv[1] + rv[2] + rv[3]);
        atomicAdd(&acc2[1], rs2[0] + rs2[1] + rs2[2] + rs2[3]);
    }
}

// ---------------------------------------------------------------------------
extern "C" void kernel_launch(void* const* d_in, const int* in_sizes, int n_in,
                              void* d_out, int out_size, void* d_ws, size_t ws_size,
                              hipStream_t stream) {
    const float* preds   = (const float*)d_in[0];
    const float* targets = (const float*)d_in[1];
    const float* ctemps  = (const float*)d_in[2];
    const int*   adj     = (const int*)d_in[3];
    float* out = (float*)d_out;

    long zz = in_sizes[3];
    int Z = (int)llround(sqrt((double)zz));
    int B = in_sizes[1] / Z;

    size_t off = 0;
    size_t maskOff = off; off += (size_t)Z * Z;          // fp8 mask
    size_t cf8Off  = off; off += (size_t)B * Z;          // fp8 ctemps
    size_t idgOff  = off; off += (size_t)Z * 4;
    size_t hnbOff  = off; off += (size_t)Z * 4;
    int nblk = (Z > 0 && B > 0 && (B % BM) == 0 && (Z % BN) == 0) ? (B / BM) * (Z / BN) : 0;
    size_t partOff = off; off += (size_t)(nblk > 0 ? nblk : 1) * 2 * 4;

    bool main_ok = (B % BM == 0) && (Z % BN == 0) && (Z % BKE == 0) &&
                   (((Z / BKE) % 2) == 0) && ((B * Z) % 16 == 0) && (ws_size >= off);

    float invBZ = (float)(1.0 / ((double)B * (double)Z));

    if (main_ok) {
        char* ws = (char*)d_ws;
        unsigned char* maskf8 = (unsigned char*)(ws + maskOff);
        unsigned char* cf8    = (unsigned char*)(ws + cf8Off);
        float* idg      = (float*)(ws + idgOff);
        float* hnb      = (float*)(ws + hnbOff);
        float* partials = (float*)(ws + partOff);

        long n16 = (long)B * Z / 16;
        int ncb = 2048;
        k_prepconv<<<Z + ncb, 256, 0, stream>>>(adj, maskf8, idg, hnb, Z,
                                                ctemps, (uint4*)cf8, n16, ncb);
        k_gemm<<<nblk, NT, 0, stream>>>(cf8, maskf8, preds, targets, ctemps, idg, hnb,
                                        partials, B, Z, Z);
        k_finalize<<<1, 256, 0, stream>>>(partials, nblk, out, invBZ);
    } else {
        float* acc2 = (float*)d_ws;
        k_zero2<<<1, 64, 0, stream>>>(acc2);
        int nzb = (Z + 255) / 256;
        k_fallback<<<B * nzb, 256, (size_t)Z * 4, stream>>>(preds, targets, ctemps, adj, acc2, B, Z);
        k_finalize<<<1, 256, 0, stream>>>(acc2, 1, out, invBZ);
    }
}

// Round 18
// 187.223 us; speedup vs baseline: 1.1674x; 1.0878x over previous
//
#include <hip/hip_runtime.h>
#include <hip/hip_bf16.h>
#include <cmath>

#define BETA 0.3f
#define LAMBDA_PHY 0.15f

#define BM 128
#define BN 128
#define BKE 128          // K elems per tile (fp8 -> 128 B rows, 8x16B slots)
#define NT 512

typedef float f32x4 __attribute__((ext_vector_type(4)));
typedef int   i32x4 __attribute__((ext_vector_type(4)));
typedef int   i32x8 __attribute__((ext_vector_type(8)));

#define AS1 __attribute__((address_space(1)))
#define AS3 __attribute__((address_space(3)))

#define FENCE() asm volatile("" ::: "memory")
#define BARRIER() do { FENCE(); __builtin_amdgcn_s_barrier(); FENCE(); } while (0)
#define WAITV4() asm volatile("s_waitcnt vmcnt(4)" ::: "memory")
#define WAITV0() asm volatile("s_waitcnt vmcnt(0)" ::: "memory")

__device__ __forceinline__ float softplus_f(float x) {
    return fmaxf(x, 0.0f) + __logf(1.0f + __expf(-fabsf(x)));
}

__device__ __forceinline__ float smooth_l1_f(float d) {
    float ad = fabsf(d);
    return (ad < BETA) ? (0.5f / BETA) * d * d : (ad - 0.5f * BETA);
}

// e4m3fn encode (RNE, saturating) — exact bit manipulation.
__device__ __forceinline__ unsigned f_e4m3(float f) {
    unsigned u = __builtin_bit_cast(unsigned, f);
    unsigned s = (u >> 24) & 0x80u;
    unsigned ab = u & 0x7fffffffu;
    float a = __builtin_bit_cast(float, ab);
    if (a >= 448.f) return s | 0x7Eu;
    if (a < 0.015625f) {                       // below min normal 2^-6 -> subnormal
        int q = (int)rintf(a * 512.f);         // lsb 2^-9; q==8 -> 0x08 == 2^-6
        return s | (unsigned)q;
    }
    unsigned r = ab + 0x7FFFFu + ((ab >> 20) & 1u);   // RNE at 3 mantissa bits
    unsigned ee = (r >> 23) - 120u;                    // e-127+7
    unsigned m = (r >> 20) & 7u;
    return s | (ee << 3) | m;
}

// ---------------------------------------------------------------------------
// Kernel 1 (fused): blocks [0,Z): adjacency row -> e4m3 mask + invdeg + hasnb.
//                   blocks [Z,Z+ncb): ctemps fp32 -> e4m3 (16 elems/thread).
__global__ void k_prepconv(const int* __restrict__ adj, unsigned char* __restrict__ maskf8,
                           float* __restrict__ invdeg, float* __restrict__ hasnb, int Z,
                           const float* __restrict__ src, uint4* __restrict__ dst,
                           long n16, int ncb) {
    int t = threadIdx.x;
    if ((int)blockIdx.x < Z) {
        int z = blockIdx.x;
        const int* row = adj + (size_t)z * Z;
        unsigned char* mrow = maskf8 + (size_t)z * Z;
        int cnt = 0;
        for (int n = t; n < Z; n += blockDim.x) {
            int a = (row[n] > 0);
            mrow[n] = a ? (unsigned char)0x38 : (unsigned char)0;   // e4m3 1.0 / 0.0
            cnt += a;
        }
        for (int o = 32; o; o >>= 1) cnt += __shfl_down(cnt, o);
        __shared__ int rs[4];
        int lane = t & 63, wave = t >> 6;
        if (lane == 0) rs[wave] = cnt;
        __syncthreads();
        if (t == 0) {
            int deg = rs[0] + rs[1] + rs[2] + rs[3];
            invdeg[z] = (deg > 0) ? 1.0f / (float)deg : 1.0f;
            hasnb[z]  = (deg > 0) ? 1.0f : 0.0f;
        }
    } else {
        long i = (long)(blockIdx.x - Z) * blockDim.x + t;
        long stride = (long)ncb * blockDim.x;
        for (; i < n16; i += stride) {
            const float4* s = (const float4*)(src + i * 16);
            uint4 o;
            unsigned w[4];
#pragma unroll
            for (int q = 0; q < 4; ++q) {
                float4 v = s[q];
                w[q] = f_e4m3(v.x) | (f_e4m3(v.y) << 8) | (f_e4m3(v.z) << 16) | (f_e4m3(v.w) << 24);
            }
            o.x = w[0]; o.y = w[1]; o.z = w[2]; o.w = w[3];
            dst[i] = o;
        }
    }
}

// ---------------------------------------------------------------------------
// Kernel 2: 128x128 fp8(e4m3) GEMM via MX-scaled MFMA (16x16x128, unit
// scales 0x7F = 2^0), BK=128 elems, 8 waves (2x4), per-wave 64x32 out,
// 2 blocks/CU. R18 change vs R17: the whole K=128 tile is ONE MFMA per
// 16x16 output (8 instr/tile/wave vs 32) — halves MFMA-pipe demand at the
// measured 2x MX rate (4661 TF). Operand = lane's existing slots {fq, fq+4}
// assembled into v8i32; A and B use the SAME k-mapping so any internal
// k-ordering is a consistent permutation -> dot product exact (R15 argument).
// ds_read pattern unchanged (verified conflict-free XOR swizzle, 12 b128).
__global__ __launch_bounds__(NT, 4) void k_gemm(
    const unsigned char* __restrict__ Af8,    // [M][K] e4m3 ctemps
    const unsigned char* __restrict__ Bf8,    // [N][K] e4m3 mask
    const float* __restrict__ preds,
    const float* __restrict__ targets,
    const float* __restrict__ ctemps,         // fp32 (epilogue c)
    const float* __restrict__ invdeg,
    const float* __restrict__ hasnb,
    float* __restrict__ partials,
    int M, int N, int K)
{
    __shared__ __align__(16) unsigned char AsF[2 * BM * BKE];   // 32 KB
    __shared__ __align__(16) unsigned char BsF[2 * BN * BKE];   // 32 KB

    const int nwg = gridDim.x;
    const int ob = blockIdx.x;
    const int bid = (nwg % 8 == 0) ? ((ob % 8) * (nwg / 8) + ob / 8) : ob;  // T1
    const int ntiles = N / BN;
    const int mt = bid / ntiles;
    const int nt = bid % ntiles;
    const int row0 = mt * BM;
    const int col0 = nt * BN;
    const int t = threadIdx.x;
    const int lane = t & 63;
    const int wave = t >> 6;
    const int wm = wave >> 2;             // 2x4 wave grid; per-wave 64x32 out
    const int wn = wave & 3;
    const int fr = lane & 15;
    const int fq = lane >> 4;
    const int fr7 = fr & 7;

    // staging: thread t -> row tr (0..63, +64 2nd chunk), 16B slot tc (0..7);
    // source slot pre-swizzled (T2): cs = tc ^ (tr&7).
    const int tr = t >> 3;
    const int tc = t & 7;
    const int cs = tc ^ (tr & 7);

    // loop-invariant LDS read byte-offsets: one b128 per (row, p), logical
    // slot fq+4p, physical slot (fq+4p)^(row&7); row&7 == fr&7.
    int ofsA[2], ofsB[2];
#pragma unroll
    for (int p = 0; p < 2; ++p) {
        const int sp = (((fq + 4 * p) ^ fr7) << 4);
        ofsA[p] = (wm * 64 + fr) * BKE + sp;   // + mi*2048 (16 rows)
        ofsB[p] = (wn * 32 + fr) * BKE + sp;   // + ni*2048
    }

    f32x4 acc[4][2];
#pragma unroll
    for (int m = 0; m < 4; ++m)
#pragma unroll
        for (int n = 0; n < 2; ++n)
            acc[m][n] = (f32x4){0.f, 0.f, 0.f, 0.f};

    // per-thread byte source pointers (advance by BKE bytes per staged tile)
    const unsigned char* aSrc = Af8 + (size_t)(row0 + tr) * K + cs * 16;
    const unsigned char* bSrc = Bf8 + (size_t)(col0 + tr) * K + cs * 16;
    unsigned char* aDstC = &AsF[t * 16];
    unsigned char* bDstC = &BsF[t * 16];

#define STAGE(BUF) do {                                                                      \
    __builtin_amdgcn_global_load_lds((const AS1 void*)(aSrc),                                \
                                     (AS3 void*)(aDstC + (BUF) * 16384), 16, 0, 0);          \
    __builtin_amdgcn_global_load_lds((const AS1 void*)(aSrc + (size_t)64 * K),               \
                                     (AS3 void*)(aDstC + (BUF) * 16384 + 8192), 16, 0, 0);   \
    __builtin_amdgcn_global_load_lds((const AS1 void*)(bSrc),                                \
                                     (AS3 void*)(bDstC + (BUF) * 16384), 16, 0, 0);          \
    __builtin_amdgcn_global_load_lds((const AS1 void*)(bSrc + (size_t)64 * K),               \
                                     (AS3 void*)(bDstC + (BUF) * 16384 + 8192), 16, 0, 0);   \
    aSrc += BKE; bSrc += BKE;                                                                \
} while (0)

// One K=128 tile: 12 ds_read_b128 + 8 MX-scaled MFMA (unit scale 0x7F).
#define MFMA_TILE(BUF) do {                                                                  \
    i32x8 af_[4], bv_[2];                                                                    \
    _Pragma("unroll")                                                                        \
    for (int mi_ = 0; mi_ < 4; ++mi_) {                                                      \
        i32x4 lo_ = *(const i32x4*)(AsF + (BUF) * 16384 + ofsA[0] + mi_ * 2048);             \
        i32x4 hi_ = *(const i32x4*)(AsF + (BUF) * 16384 + ofsA[1] + mi_ * 2048);             \
        af_[mi_] = (i32x8){lo_[0], lo_[1], lo_[2], lo_[3], hi_[0], hi_[1], hi_[2], hi_[3]};  \
    }                                                                                        \
    _Pragma("unroll")                                                                        \
    for (int ni_ = 0; ni_ < 2; ++ni_) {                                                      \
        i32x4 lo_ = *(const i32x4*)(BsF + (BUF) * 16384 + ofsB[0] + ni_ * 2048);             \
        i32x4 hi_ = *(const i32x4*)(BsF + (BUF) * 16384 + ofsB[1] + ni_ * 2048);             \
        bv_[ni_] = (i32x8){lo_[0], lo_[1], lo_[2], lo_[3], hi_[0], hi_[1], hi_[2], hi_[3]};  \
    }                                                                                        \
    __builtin_amdgcn_s_setprio(1);                                                           \
    _Pragma("unroll")                                                                        \
    for (int mi_ = 0; mi_ < 4; ++mi_)                                                        \
    _Pragma("unroll")                                                                        \
    for (int ni_ = 0; ni_ < 2; ++ni_)                                                        \
        acc[mi_][ni_] = __builtin_amdgcn_mfma_scale_f32_16x16x128_f8f6f4(                    \
            af_[mi_], bv_[ni_], acc[mi_][ni_], 0, 0, 0, 0x7F, 0, 0x7F);                      \
    __builtin_amdgcn_s_setprio(0);                                                           \
} while (0)

    const int nk = K / BKE;         // 16 at Z=2048; even (guarded)
    const int nk2 = nk >> 1;
    STAGE(0);                        // tile 0 -> buf 0

    for (int i = 0; i < nk2; ++i) {
        STAGE(1);
        WAITV4();                    // retires tile 2i's 4 loads (oldest in FIFO)
        BARRIER();
        MFMA_TILE(0);
        BARRIER();
        if (i + 1 < nk2) {
            STAGE(0);
            WAITV4();
        } else {
            WAITV0();
        }
        BARRIER();
        MFMA_TILE(1);
        BARRIER();
    }

#undef STAGE
#undef MFMA_TILE

    // Batched fused epilogue: 4 batches x 8 outputs (24 loads then compute).
    // C/D layout: col=lane&15, row=(lane>>4)*4+reg.
    // block row = wm*64 + m*16 + fq*4 + j ; block col = wn*32 + n*16 + fr
    const size_t rbase = (size_t)(row0 + wm * 64 + fq * 4) * N;
    const float* pB = preds   + rbase;
    const float* tB = targets + rbase;
    const float* cB = ctemps  + rbase;

    float vsum = 0.f, ssum = 0.f;
#pragma unroll
    for (int n = 0; n < 2; ++n) {
        const int z = col0 + wn * 32 + n * 16 + fr;
        const float idg = invdeg[z];
        const float hnb = hasnb[z];
#pragma unroll
        for (int mb = 0; mb < 2; ++mb) {
            float pv[8], tv[8], cf[8];
#pragma unroll
            for (int m2 = 0; m2 < 2; ++m2)
#pragma unroll
                for (int j = 0; j < 4; ++j) {
                    const size_t o = (size_t)((mb * 2 + m2) * 16 + j) * N + z;
                    pv[m2 * 4 + j] = pB[o];
                    tv[m2 * 4 + j] = tB[o];
                    cf[m2 * 4 + j] = cB[o];
                }
#pragma unroll
            for (int m2 = 0; m2 < 2; ++m2)
#pragma unroll
                for (int j = 0; j < 4; ++j) {
                    const int q = m2 * 4 + j;
                    float avg = acc[mb * 2 + m2][n][j] * idg;
                    float c = cf[q];
                    float p = pv[q];
                    float x = (c - avg) * (p - c);
                    vsum += softplus_f(x) * hnb;
                    ssum += smooth_l1_f(p - tv[q]);
                }
        }
    }
    for (int o = 32; o; o >>= 1) { vsum += __shfl_down(vsum, o); ssum += __shfl_down(ssum, o); }
    __shared__ float rv[8], rsm[8];
    if (lane == 0) { rv[wave] = vsum; rsm[wave] = ssum; }
    __syncthreads();
    if (t == 0) {
        float v = 0.f, s = 0.f;
#pragma unroll
        for (int w = 0; w < 8; ++w) { v += rv[w]; s += rsm[w]; }
        partials[2 * (size_t)ob]     = v;
        partials[2 * (size_t)ob + 1] = s;
    }
}

// ---------------------------------------------------------------------------
// Kernel 3: deterministic fixed-order final reduction
__global__ void k_finalize(const float* __restrict__ partials, int nblk,
                           float* __restrict__ out, float invBZ) {
    __shared__ float sv[256], ss[256];
    int t = threadIdx.x;
    float v = 0.f, s = 0.f;
    for (int i = t; i < nblk; i += 256) { v += partials[2 * (size_t)i]; s += partials[2 * (size_t)i + 1]; }
    sv[t] = v; ss[t] = s;
    __syncthreads();
    for (int o = 128; o; o >>= 1) {
        if (t < o) { sv[t] += sv[t + o]; ss[t] += ss[t + o]; }
        __syncthreads();
    }
    if (t == 0) {
        float phys = sv[0] * invBZ;
        float pred = ss[0] * invBZ;
        out[0] = pred + LAMBDA_PHY * phys;
        out[1] = phys;
    }
}

// ---------------------------------------------------------------------------
// Fallback path (only if ws too small / odd shapes): fp32, atomics into ws[0..1]
__global__ void k_zero2(float* p) { if (threadIdx.x < 2) p[threadIdx.x] = 0.f; }

__global__ void k_fallback(const float* __restrict__ preds, const float* __restrict__ targets,
                           const float* __restrict__ ctemps, const int* __restrict__ adj,
                           float* __restrict__ acc2, int B, int Z) {
    extern __shared__ float crow[];
    int nzb = (Z + 255) / 256;
    int b = blockIdx.x / nzb;
    int zb = blockIdx.x % nzb;
    int t = threadIdx.x;
    const float* cr = ctemps + (size_t)b * Z;
    for (int n = t; n < Z; n += 256) crow[n] = cr[n];
    __syncthreads();
    int z = zb * 256 + t;
    float vsum = 0.f, ssum = 0.f;
    if (z < Z) {
        const int* arow = adj + (size_t)z * Z;
        float sum = 0.f; int deg = 0;
        for (int n = 0; n < Z; ++n) {
            if (arow[n] > 0) { sum += crow[n]; ++deg; }
        }
        float avg = (deg > 0) ? sum / (float)deg : 0.f;
        float c = crow[z];
        size_t idx = (size_t)b * Z + z;
        float p = preds[idx];
        float x = (c - avg) * (p - c);
        vsum = (deg > 0) ? softplus_f(x) : 0.f;
        ssum = smooth_l1_f(p - targets[idx]);
    }
    for (int o = 32; o; o >>= 1) { vsum += __shfl_down(vsum, o); ssum += __shfl_down(ssum, o); }
    __shared__ float rv[4], rs2[4];
    int lane = t & 63, wave = t >> 6;
    if (lane == 0) { rv[wave] = vsum; rs2[wave] = ssum; }
    __syncthreads();
    if (t == 0) {
        atomicAdd(&acc2[0], rv[0] + rv[1] + rv[2] + rv[3]);
        atomicAdd(&acc2[1], rs2[0] + rs2[1] + rs2[2] + rs2[3]);
    }
}

// ---------------------------------------------------------------------------
extern "C" void kernel_launch(void* const* d_in, const int* in_sizes, int n_in,
                              void* d_out, int out_size, void* d_ws, size_t ws_size,
                              hipStream_t stream) {
    const float* preds   = (const float*)d_in[0];
    const float* targets = (const float*)d_in[1];
    const float* ctemps  = (const float*)d_in[2];
    const int*   adj     = (const int*)d_in[3];
    float* out = (float*)d_out;

    long zz = in_sizes[3];
    int Z = (int)llround(sqrt((double)zz));
    int B = in_sizes[1] / Z;

    size_t off = 0;
    size_t maskOff = off; off += (size_t)Z * Z;          // fp8 mask
    size_t cf8Off  = off; off += (size_t)B * Z;          // fp8 ctemps
    size_t idgOff  = off; off += (size_t)Z * 4;
    size_t hnbOff  = off; off += (size_t)Z * 4;
    int nblk = (Z > 0 && B > 0 && (B % BM) == 0 && (Z % BN) == 0) ? (B / BM) * (Z / BN) : 0;
    size_t partOff = off; off += (size_t)(nblk > 0 ? nblk : 1) * 2 * 4;

    bool main_ok = (B % BM == 0) && (Z % BN == 0) && (Z % BKE == 0) &&
                   (((Z / BKE) % 2) == 0) && ((B * Z) % 16 == 0) && (ws_size >= off);

    float invBZ = (float)(1.0 / ((double)B * (double)Z));

    if (main_ok) {
        char* ws = (char*)d_ws;
        unsigned char* maskf8 = (unsigned char*)(ws + maskOff);
        unsigned char* cf8    = (unsigned char*)(ws + cf8Off);
        float* idg      = (float*)(ws + idgOff);
        float* hnb      = (float*)(ws + hnbOff);
        float* partials = (float*)(ws + partOff);

        long n16 = (long)B * Z / 16;
        int ncb = 2048;
        k_prepconv<<<Z + ncb, 256, 0, stream>>>(adj, maskf8, idg, hnb, Z,
                                                ctemps, (uint4*)cf8, n16, ncb);
        k_gemm<<<nblk, NT, 0, stream>>>(cf8, maskf8, preds, targets, ctemps, idg, hnb,
                                        partials, B, Z, Z);
        k_finalize<<<1, 256, 0, stream>>>(partials, nblk, out, invBZ);
    } else {
        float* acc2 = (float*)d_ws;
        k_zero2<<<1, 64, 0, stream>>>(acc2);
        int nzb = (Z + 255) / 256;
        k_fallback<<<B * nzb, 256, (size_t)Z * 4, stream>>>(preds, targets, ctemps, adj, acc2, B, Z);
        k_finalize<<<1, 256, 0, stream>>>(acc2, 1, out, invBZ);
    }
}

// Round 19
// 186.860 us; speedup vs baseline: 1.1696x; 1.0019x over previous
//
#include <hip/hip_runtime.h>
#include <hip/hip_bf16.h>
#include <cmath>

#define BETA 0.3f
#define LAMBDA_PHY 0.15f

#define BM 128
#define BN 128
#define BKE 128          // K elems per tile (fp8 -> 128 B rows, 8x16B slots)
#define NT 256

typedef float f32x4 __attribute__((ext_vector_type(4)));
typedef int   i32x4 __attribute__((ext_vector_type(4)));
typedef int   i32x8 __attribute__((ext_vector_type(8)));

#define AS1 __attribute__((address_space(1)))
#define AS3 __attribute__((address_space(3)))

#define FENCE() asm volatile("" ::: "memory")
#define BARRIER() do { FENCE(); __builtin_amdgcn_s_barrier(); FENCE(); } while (0)
#define WAITV8() asm volatile("s_waitcnt vmcnt(8)" ::: "memory")
#define WAITV0() asm volatile("s_waitcnt vmcnt(0)" ::: "memory")

__device__ __forceinline__ float softplus_f(float x) {
    return fmaxf(x, 0.0f) + __logf(1.0f + __expf(-fabsf(x)));
}

__device__ __forceinline__ float smooth_l1_f(float d) {
    float ad = fabsf(d);
    return (ad < BETA) ? (0.5f / BETA) * d * d : (ad - 0.5f * BETA);
}

// e4m3fn encode (RNE, saturating) — exact bit manipulation.
__device__ __forceinline__ unsigned f_e4m3(float f) {
    unsigned u = __builtin_bit_cast(unsigned, f);
    unsigned s = (u >> 24) & 0x80u;
    unsigned ab = u & 0x7fffffffu;
    float a = __builtin_bit_cast(float, ab);
    if (a >= 448.f) return s | 0x7Eu;
    if (a < 0.015625f) {                       // below min normal 2^-6 -> subnormal
        int q = (int)rintf(a * 512.f);         // lsb 2^-9; q==8 -> 0x08 == 2^-6
        return s | (unsigned)q;
    }
    unsigned r = ab + 0x7FFFFu + ((ab >> 20) & 1u);   // RNE at 3 mantissa bits
    unsigned ee = (r >> 23) - 120u;                    // e-127+7
    unsigned m = (r >> 20) & 7u;
    return s | (ee << 3) | m;
}

// ---------------------------------------------------------------------------
// Kernel 1 (fused): blocks [0,Z): adjacency row -> e4m3 mask + invdeg + hasnb.
//                   blocks [Z,Z+ncb): ctemps fp32 -> e4m3 (16 elems/thread).
__global__ void k_prepconv(const int* __restrict__ adj, unsigned char* __restrict__ maskf8,
                           float* __restrict__ invdeg, float* __restrict__ hasnb, int Z,
                           const float* __restrict__ src, uint4* __restrict__ dst,
                           long n16, int ncb) {
    int t = threadIdx.x;
    if ((int)blockIdx.x < Z) {
        int z = blockIdx.x;
        const int* row = adj + (size_t)z * Z;
        unsigned char* mrow = maskf8 + (size_t)z * Z;
        int cnt = 0;
        for (int n = t; n < Z; n += blockDim.x) {
            int a = (row[n] > 0);
            mrow[n] = a ? (unsigned char)0x38 : (unsigned char)0;   // e4m3 1.0 / 0.0
            cnt += a;
        }
        for (int o = 32; o; o >>= 1) cnt += __shfl_down(cnt, o);
        __shared__ int rs[4];
        int lane = t & 63, wave = t >> 6;
        if (lane == 0) rs[wave] = cnt;
        __syncthreads();
        if (t == 0) {
            int deg = rs[0] + rs[1] + rs[2] + rs[3];
            invdeg[z] = (deg > 0) ? 1.0f / (float)deg : 1.0f;
            hasnb[z]  = (deg > 0) ? 1.0f : 0.0f;
        }
    } else {
        long i = (long)(blockIdx.x - Z) * blockDim.x + t;
        long stride = (long)ncb * blockDim.x;
        for (; i < n16; i += stride) {
            const float4* s = (const float4*)(src + i * 16);
            uint4 o;
            unsigned w[4];
#pragma unroll
            for (int q = 0; q < 4; ++q) {
                float4 v = s[q];
                w[q] = f_e4m3(v.x) | (f_e4m3(v.y) << 8) | (f_e4m3(v.z) << 16) | (f_e4m3(v.w) << 24);
            }
            o.x = w[0]; o.y = w[1]; o.z = w[2]; o.w = w[3];
            dst[i] = o;
        }
    }
}

// ---------------------------------------------------------------------------
// Kernel 2: 128x128 fp8(e4m3) GEMM via MX-scaled MFMA (16x16x128, unit
// scales 0x7F), 4 waves (2x2), per-wave 64x64 out, 2 blocks/CU.
// R19 vs R18: 64x64/wave cuts LDS read traffic 33% (each A byte read by 2
// waves, was 4): per tile/block 96->64 KB reads; 16 b128 + 16 MFMA per
// wave/tile (1:1). R18 decomposition showed LDS port (~78us) as the largest
// demand. Same verified pieces: XOR swizzle, counted vmcnt(8), compile-time
// buffer unroll, T1 XCD swizzle, setprio, batch-8 epilogue.
__global__ __launch_bounds__(NT, 2) void k_gemm(
    const unsigned char* __restrict__ Af8,    // [M][K] e4m3 ctemps
    const unsigned char* __restrict__ Bf8,    // [N][K] e4m3 mask
    const float* __restrict__ preds,
    const float* __restrict__ targets,
    const float* __restrict__ ctemps,         // fp32 (epilogue c)
    const float* __restrict__ invdeg,
    const float* __restrict__ hasnb,
    float* __restrict__ partials,
    int M, int N, int K)
{
    __shared__ __align__(16) unsigned char AsF[2 * BM * BKE];   // 32 KB
    __shared__ __align__(16) unsigned char BsF[2 * BN * BKE];   // 32 KB

    const int nwg = gridDim.x;
    const int ob = blockIdx.x;
    const int bid = (nwg % 8 == 0) ? ((ob % 8) * (nwg / 8) + ob / 8) : ob;  // T1
    const int ntiles = N / BN;
    const int mt = bid / ntiles;
    const int nt = bid % ntiles;
    const int row0 = mt * BM;
    const int col0 = nt * BN;
    const int t = threadIdx.x;
    const int lane = t & 63;
    const int wave = t >> 6;
    const int wm = wave >> 1;             // 2x2 wave grid; per-wave 64x64 out
    const int wn = wave & 1;
    const int fr = lane & 15;
    const int fq = lane >> 4;
    const int fr7 = fr & 7;

    // staging: thread t -> row tr (0..31, +32 per chunk, 4 chunks), slot tc;
    // source slot pre-swizzled (T2): cs = tc ^ (tr&7); 32%8==0 keeps it valid.
    const int tr = t >> 3;                // 0..31
    const int tc = t & 7;                 // 16B slot 0..7
    const int cs = tc ^ (tr & 7);

    // loop-invariant LDS read byte-offsets: one b128 per (row, p), logical
    // slot fq+4p, physical slot (fq+4p)^(row&7); row&7 == fr&7.
    int ofsA[2], ofsB[2];
#pragma unroll
    for (int p = 0; p < 2; ++p) {
        const int sp = (((fq + 4 * p) ^ fr7) << 4);
        ofsA[p] = (wm * 64 + fr) * BKE + sp;   // + mi*2048 (16 rows)
        ofsB[p] = (wn * 64 + fr) * BKE + sp;   // + ni*2048
    }

    f32x4 acc[4][4];
#pragma unroll
    for (int m = 0; m < 4; ++m)
#pragma unroll
        for (int n = 0; n < 4; ++n)
            acc[m][n] = (f32x4){0.f, 0.f, 0.f, 0.f};

    // per-thread byte source pointers (advance by BKE bytes per staged tile)
    const unsigned char* aSrc = Af8 + (size_t)(row0 + tr) * K + cs * 16;
    const unsigned char* bSrc = Bf8 + (size_t)(col0 + tr) * K + cs * 16;
    unsigned char* aDstC = &AsF[t * 16];
    unsigned char* bDstC = &BsF[t * 16];

#define STAGE(BUF) do {                                                                      \
    _Pragma("unroll")                                                                        \
    for (int r_ = 0; r_ < 4; ++r_)                                                           \
        __builtin_amdgcn_global_load_lds((const AS1 void*)(aSrc + (size_t)(r_ * 32) * K),    \
                                         (AS3 void*)(aDstC + (BUF) * 16384 + r_ * 4096), 16, 0, 0); \
    _Pragma("unroll")                                                                        \
    for (int r_ = 0; r_ < 4; ++r_)                                                           \
        __builtin_amdgcn_global_load_lds((const AS1 void*)(bSrc + (size_t)(r_ * 32) * K),    \
                                         (AS3 void*)(bDstC + (BUF) * 16384 + r_ * 4096), 16, 0, 0); \
    aSrc += BKE; bSrc += BKE;                                                                \
} while (0)

// One K=128 tile: 16 ds_read_b128 + 16 MX-scaled MFMA (unit scale 0x7F).
#define MFMA_TILE(BUF) do {                                                                  \
    i32x8 af_[4], bv_[4];                                                                    \
    _Pragma("unroll")                                                                        \
    for (int mi_ = 0; mi_ < 4; ++mi_) {                                                      \
        i32x4 lo_ = *(const i32x4*)(AsF + (BUF) * 16384 + ofsA[0] + mi_ * 2048);             \
        i32x4 hi_ = *(const i32x4*)(AsF + (BUF) * 16384 + ofsA[1] + mi_ * 2048);             \
        af_[mi_] = (i32x8){lo_[0], lo_[1], lo_[2], lo_[3], hi_[0], hi_[1], hi_[2], hi_[3]};  \
    }                                                                                        \
    _Pragma("unroll")                                                                        \
    for (int ni_ = 0; ni_ < 4; ++ni_) {                                                      \
        i32x4 lo_ = *(const i32x4*)(BsF + (BUF) * 16384 + ofsB[0] + ni_ * 2048);             \
        i32x4 hi_ = *(const i32x4*)(BsF + (BUF) * 16384 + ofsB[1] + ni_ * 2048);             \
        bv_[ni_] = (i32x8){lo_[0], lo_[1], lo_[2], lo_[3], hi_[0], hi_[1], hi_[2], hi_[3]};  \
    }                                                                                        \
    __builtin_amdgcn_s_setprio(1);                                                           \
    _Pragma("unroll")                                                                        \
    for (int mi_ = 0; mi_ < 4; ++mi_)                                                        \
    _Pragma("unroll")                                                                        \
    for (int ni_ = 0; ni_ < 4; ++ni_)                                                        \
        acc[mi_][ni_] = __builtin_amdgcn_mfma_scale_f32_16x16x128_f8f6f4(                    \
            af_[mi_], bv_[ni_], acc[mi_][ni_], 0, 0, 0, 0x7F, 0, 0x7F);                      \
    __builtin_amdgcn_s_setprio(0);                                                           \
} while (0)

    const int nk = K / BKE;         // 16 at Z=2048; even (guarded)
    const int nk2 = nk >> 1;
    STAGE(0);                        // tile 0 -> buf 0

    for (int i = 0; i < nk2; ++i) {
        STAGE(1);
        WAITV8();                    // retires tile 2i's 8 loads (oldest in FIFO)
        BARRIER();
        MFMA_TILE(0);
        BARRIER();
        if (i + 1 < nk2) {
            STAGE(0);
            WAITV8();
        } else {
            WAITV0();
        }
        BARRIER();
        MFMA_TILE(1);
        BARRIER();
    }

#undef STAGE
#undef MFMA_TILE

    // Batched fused epilogue: 8 batches x 8 outputs (24 loads then compute).
    // C/D layout: col=lane&15, row=(lane>>4)*4+reg.
    // block row = wm*64 + m*16 + fq*4 + j ; block col = wn*64 + n*16 + fr
    const size_t rbase = (size_t)(row0 + wm * 64 + fq * 4) * N;
    const float* pB = preds   + rbase;
    const float* tB = targets + rbase;
    const float* cB = ctemps  + rbase;

    float vsum = 0.f, ssum = 0.f;
#pragma unroll
    for (int n = 0; n < 4; ++n) {
        const int z = col0 + wn * 64 + n * 16 + fr;
        const float idg = invdeg[z];
        const float hnb = hasnb[z];
#pragma unroll
        for (int mb = 0; mb < 2; ++mb) {
            float pv[8], tv[8], cf[8];
#pragma unroll
            for (int m2 = 0; m2 < 2; ++m2)
#pragma unroll
                for (int j = 0; j < 4; ++j) {
                    const size_t o = (size_t)((mb * 2 + m2) * 16 + j) * N + z;
                    pv[m2 * 4 + j] = pB[o];
                    tv[m2 * 4 + j] = tB[o];
                    cf[m2 * 4 + j] = cB[o];
                }
#pragma unroll
            for (int m2 = 0; m2 < 2; ++m2)
#pragma unroll
                for (int j = 0; j < 4; ++j) {
                    const int q = m2 * 4 + j;
                    float avg = acc[mb * 2 + m2][n][j] * idg;
                    float c = cf[q];
                    float p = pv[q];
                    float x = (c - avg) * (p - c);
                    vsum += softplus_f(x) * hnb;
                    ssum += smooth_l1_f(p - tv[q]);
                }
        }
    }
    for (int o = 32; o; o >>= 1) { vsum += __shfl_down(vsum, o); ssum += __shfl_down(ssum, o); }
    __shared__ float rv[4], rsm[4];
    if (lane == 0) { rv[wave] = vsum; rsm[wave] = ssum; }
    __syncthreads();
    if (t == 0) {
        partials[2 * (size_t)ob]     = rv[0] + rv[1] + rv[2] + rv[3];
        partials[2 * (size_t)ob + 1] = rsm[0] + rsm[1] + rsm[2] + rsm[3];
    }
}

// ---------------------------------------------------------------------------
// Kernel 3: deterministic fixed-order final reduction
__global__ void k_finalize(const float* __restrict__ partials, int nblk,
                           float* __restrict__ out, float invBZ) {
    __shared__ float sv[256], ss[256];
    int t = threadIdx.x;
    float v = 0.f, s = 0.f;
    for (int i = t; i < nblk; i += 256) { v += partials[2 * (size_t)i]; s += partials[2 * (size_t)i + 1]; }
    sv[t] = v; ss[t] = s;
    __syncthreads();
    for (int o = 128; o; o >>= 1) {
        if (t < o) { sv[t] += sv[t + o]; ss[t] += ss[t + o]; }
        __syncthreads();
    }
    if (t == 0) {
        float phys = sv[0] * invBZ;
        float pred = ss[0] * invBZ;
        out[0] = pred + LAMBDA_PHY * phys;
        out[1] = phys;
    }
}

// ---------------------------------------------------------------------------
// Fallback path (only if ws too small / odd shapes): fp32, atomics into ws[0..1]
__global__ void k_zero2(float* p) { if (threadIdx.x < 2) p[threadIdx.x] = 0.f; }

__global__ void k_fallback(const float* __restrict__ preds, const float* __restrict__ targets,
                           const float* __restrict__ ctemps, const int* __restrict__ adj,
                           float* __restrict__ acc2, int B, int Z) {
    extern __shared__ float crow[];
    int nzb = (Z + 255) / 256;
    int b = blockIdx.x / nzb;
    int zb = blockIdx.x % nzb;
    int t = threadIdx.x;
    const float* cr = ctemps + (size_t)b * Z;
    for (int n = t; n < Z; n += 256) crow[n] = cr[n];
    __syncthreads();
    int z = zb * 256 + t;
    float vsum = 0.f, ssum = 0.f;
    if (z < Z) {
        const int* arow = adj + (size_t)z * Z;
        float sum = 0.f; int deg = 0;
        for (int n = 0; n < Z; ++n) {
            if (arow[n] > 0) { sum += crow[n]; ++deg; }
        }
        float avg = (deg > 0) ? sum / (float)deg : 0.f;
        float c = crow[z];
        size_t idx = (size_t)b * Z + z;
        float p = preds[idx];
        float x = (c - avg) * (p - c);
        vsum = (deg > 0) ? softplus_f(x) : 0.f;
        ssum = smooth_l1_f(p - targets[idx]);
    }
    for (int o = 32; o; o >>= 1) { vsum += __shfl_down(vsum, o); ssum += __shfl_down(ssum, o); }
    __shared__ float rv[4], rs2[4];
    int lane = t & 63, wave = t >> 6;
    if (lane == 0) { rv[wave] = vsum; rs2[wave] = ssum; }
    __syncthreads();
    if (t == 0) {
        atomicAdd(&acc2[0], rv[0] + rv[1] + rv[2] + rv[3]);
        atomicAdd(&acc2[1], rs2[0] + rs2[1] + rs2[2] + rs2[3]);
    }
}

// ---------------------------------------------------------------------------
extern "C" void kernel_launch(void* const* d_in, const int* in_sizes, int n_in,
                              void* d_out, int out_size, void* d_ws, size_t ws_size,
                              hipStream_t stream) {
    const float* preds   = (const float*)d_in[0];
    const float* targets = (const float*)d_in[1];
    const float* ctemps  = (const float*)d_in[2];
    const int*   adj     = (const int*)d_in[3];
    float* out = (float*)d_out;

    long zz = in_sizes[3];
    int Z = (int)llround(sqrt((double)zz));
    int B = in_sizes[1] / Z;

    size_t off = 0;
    size_t maskOff = off; off += (size_t)Z * Z;          // fp8 mask
    size_t cf8Off  = off; off += (size_t)B * Z;          // fp8 ctemps
    size_t idgOff  = off; off += (size_t)Z * 4;
    size_t hnbOff  = off; off += (size_t)Z * 4;
    int nblk = (Z > 0 && B > 0 && (B % BM) == 0 && (Z % BN) == 0) ? (B / BM) * (Z / BN) : 0;
    size_t partOff = off; off += (size_t)(nblk > 0 ? nblk : 1) * 2 * 4;

    bool main_ok = (B % BM == 0) && (Z % BN == 0) && (Z % BKE == 0) &&
                   (((Z / BKE) % 2) == 0) && ((B * Z) % 16 == 0) && (ws_size >= off);

    float invBZ = (float)(1.0 / ((double)B * (double)Z));

    if (main_ok) {
        char* ws = (char*)d_ws;
        unsigned char* maskf8 = (unsigned char*)(ws + maskOff);
        unsigned char* cf8    = (unsigned char*)(ws + cf8Off);
        float* idg      = (float*)(ws + idgOff);
        float* hnb      = (float*)(ws + hnbOff);
        float* partials = (float*)(ws + partOff);

        long n16 = (long)B * Z / 16;
        int ncb = 2048;
        k_prepconv<<<Z + ncb, 256, 0, stream>>>(adj, maskf8, idg, hnb, Z,
                                                ctemps, (uint4*)cf8, n16, ncb);
        k_gemm<<<nblk, NT, 0, stream>>>(cf8, maskf8, preds, targets, ctemps, idg, hnb,
                                        partials, B, Z, Z);
        k_finalize<<<1, 256, 0, stream>>>(partials, nblk, out, invBZ);
    } else {
        float* acc2 = (float*)d_ws;
        k_zero2<<<1, 64, 0, stream>>>(acc2);
        int nzb = (Z + 255) / 256;
        k_fallback<<<B * nzb, 256, (size_t)Z * 4, stream>>>(preds, targets, ctemps, adj, acc2, B, Z);
        k_finalize<<<1, 256, 0, stream>>>(acc2, 1, out, invBZ);
    }
}